// Round 3
// baseline (24445.934 us; speedup 1.0000x reference)
//
#include <hip/hip_runtime.h>

#define T_STEPS 2048
#define NWG 64

typedef __bf16 bf16x8 __attribute__((ext_vector_type(8)));
typedef float f32x4 __attribute__((ext_vector_type(4)));

// ws layout
#define XBF_OFF   0ull                       // [2048][32][256] bf16 = 33554432 B
#define BAR_OFF   33554432ull                // barrier counter (256 B zeroed)
#define HBUF_OFF  33558528ull                // [dir][buf][32][512] bf16 = 131072 B
#define WS_NEEDED (HBUF_OFF + 131072ull)

__device__ __forceinline__ unsigned short f2bf(float f) {
    unsigned int u = __builtin_bit_cast(unsigned int, f);
    u = u + 0x7fffu + ((u >> 16) & 1u);
    return (unsigned short)(u >> 16);
}
__device__ __forceinline__ float sigf(float x) { return 1.0f / (1.0f + __expf(-x)); }
__device__ __forceinline__ float tanhfast(float x) { return 1.0f - 2.0f / (__expf(2.0f * x) + 1.0f); }

// X: [32][2048][256] fp32 -> Xbf: [2048][32][256] bf16
__global__ void prep_x(const float* __restrict__ X, unsigned short* __restrict__ Xbf) {
    unsigned int idx = blockIdx.x * 256u + threadIdx.x;   // 4,194,304 total, 4 elems each
    unsigned int k4 = idx & 63u;
    unsigned int b  = (idx >> 6) & 31u;
    unsigned int t  = idx >> 11;
    float4 v = *(const float4*)(X + ((size_t)b * 2048u + t) * 256u + k4 * 4u);
    unsigned long long pk = (unsigned long long)f2bf(v.x)
                          | ((unsigned long long)f2bf(v.y) << 16)
                          | ((unsigned long long)f2bf(v.z) << 32)
                          | ((unsigned long long)f2bf(v.w) << 48);
    *(unsigned long long*)(Xbf + ((size_t)t * 32u + b) * 256u + k4 * 4u) = pk;
}

// Persistent recurrent kernel: 64 WGs = 2 dirs x 32 slices (16 hidden cols each).
__global__ __launch_bounds__(256, 1) void lstm_rec(
    const unsigned short* __restrict__ Xbf,
    const float* __restrict__ W_f, const float* __restrict__ U_f, const float* __restrict__ b_f,
    const float* __restrict__ W_b, const float* __restrict__ U_b, const float* __restrict__ b_b,
    float* __restrict__ out, unsigned int* bar, unsigned int* Hbuf)
{
    const int wg = blockIdx.x;
    const int d  = wg >> 5;        // 0 = forward, 1 = backward
    const int s  = wg & 31;
    const int c0 = s * 16;
    const int tid = threadIdx.x;

    const float* Wm = d ? W_b : W_f;
    const float* Um = d ? U_b : U_f;
    const float* bia = d ? b_b : b_f;

    __shared__ __align__(16) unsigned char s_u[65536];   // U slice  [64 cols][512 k] bf16, swizzled
    __shared__ __align__(16) unsigned char s_w[32768];   // W slice  [64 cols][256 k] bf16, swizzled
    __shared__ __align__(16) unsigned char s_h[32768];   // H stage  [32 b][512 k]  bf16, swizzled
    __shared__ __align__(16) unsigned char s_x[16384];   // X stage  [32 b][256 k]  bf16, swizzled
    __shared__ float s_S[32][64];                        // gate pre-activations
    __shared__ float s_bias[64];
    __shared__ int s_abort;

    // ---- prologue: stage U/W slices (fp32 global -> bf16 LDS, XOR-swizzled) ----
    {
        int cl = tid & 15, g = (tid >> 4) & 3, k0 = tid >> 6;
        int n = g * 16 + cl;
        int gcol = g * 512 + c0 + cl;
        for (int i = 0; i < 128; ++i) {
            int k = k0 + i * 4;
            unsigned short v = f2bf(Um[(size_t)k * 2048 + gcol]);
            unsigned int addr = (unsigned)(n * 1024 + k * 2) ^ (unsigned)((n & 7) << 4);
            *(unsigned short*)(s_u + addr) = v;
        }
        for (int i = 0; i < 64; ++i) {
            int k = k0 + i * 4;
            unsigned short v = f2bf(Wm[(size_t)k * 2048 + gcol]);
            unsigned int addr = (unsigned)(n * 512 + k * 2) ^ (unsigned)((n & 7) << 4);
            *(unsigned short*)(s_w + addr) = v;
        }
        if (tid < 64) s_bias[tid] = bia[(tid >> 4) * 512 + c0 + (tid & 15)];
        if (tid == 0) s_abort = 0;
        // h0 = 0
        for (int i = 0; i < 16; ++i)
            *(unsigned long long*)(s_h + (tid + i * 256) * 8) = 0ull;
        // stage x for first step
        int t_x = d ? (T_STEPS - 1) : 0;
        const unsigned long long* xsrc = (const unsigned long long*)(Xbf + (size_t)t_x * 32 * 256);
        for (int i = 0; i < 8; ++i) {
            int ch = tid + i * 256;
            int b = ch >> 6;
            unsigned int addr = (unsigned)(ch * 8) ^ (unsigned)((b & 7) << 4);
            *(unsigned long long*)(s_x + addr) = xsrc[ch];
        }
    }
    __syncthreads();

    // per-thread MFMA addressing (16x16x32 bf16: A row = l&15, k = 8*(l>>4)+j)
    const int g  = tid >> 6;          // wave == gate
    const int l  = tid & 63;
    const int cl = l & 15;
    const int h4 = l >> 4;
    const int n  = g * 16 + cl;
    // UNswizzled bases + per-lane swizzle constants (XOR applied to FULL offset)
    const unsigned int uO = (unsigned)(n * 1024 + h4 * 16);
    const unsigned int wO = (unsigned)(n * 512  + h4 * 16);
    const unsigned int nS = (unsigned)((n & 7) << 4);
    const int b0 = cl, b1 = cl + 16;
    const unsigned int hO0 = (unsigned)(b0 * 1024 + h4 * 16);
    const unsigned int hO1 = (unsigned)(b1 * 1024 + h4 * 16);
    const unsigned int xO0 = (unsigned)(b0 * 512  + h4 * 16);
    const unsigned int xO1 = (unsigned)(b1 * 512  + h4 * 16);
    const unsigned int bS0 = (unsigned)((b0 & 7) << 4);
    const unsigned int bS1 = (unsigned)((b1 & 7) << 4);

    // elementwise mapping: thread -> (batch eb, cols ecp, ecp+1)
    const int eb  = tid >> 3;
    const int ecp = (tid & 7) * 2;
    float c_reg[2] = {0.f, 0.f};

    for (int t = 0; t < T_STEPS; ++t) {
        f32x4 acc0 = {0.f, 0.f, 0.f, 0.f};
        f32x4 acc1 = {0.f, 0.f, 0.f, 0.f};
        #pragma unroll
        for (int kc = 0; kc < 8; ++kc) {       // x @ W  (K = 256)
            bf16x8 bv = *(const bf16x8*)(s_w + ((wO + kc * 64) ^ nS));
            bf16x8 a0 = *(const bf16x8*)(s_x + ((xO0 + kc * 64) ^ bS0));
            bf16x8 a1 = *(const bf16x8*)(s_x + ((xO1 + kc * 64) ^ bS1));
            acc0 = __builtin_amdgcn_mfma_f32_16x16x32_bf16(a0, bv, acc0, 0, 0, 0);
            acc1 = __builtin_amdgcn_mfma_f32_16x16x32_bf16(a1, bv, acc1, 0, 0, 0);
        }
        #pragma unroll
        for (int kc = 0; kc < 16; ++kc) {      // h @ U  (K = 512)
            bf16x8 bv = *(const bf16x8*)(s_u + ((uO + kc * 64) ^ nS));
            bf16x8 a0 = *(const bf16x8*)(s_h + ((hO0 + kc * 64) ^ bS0));
            bf16x8 a1 = *(const bf16x8*)(s_h + ((hO1 + kc * 64) ^ bS1));
            acc0 = __builtin_amdgcn_mfma_f32_16x16x32_bf16(a0, bv, acc0, 0, 0, 0);
            acc1 = __builtin_amdgcn_mfma_f32_16x16x32_bf16(a1, bv, acc1, 0, 0, 0);
        }
        // C/D layout: row = h4*4+r, col = l&15
        #pragma unroll
        for (int r = 0; r < 4; ++r) {
            s_S[h4 * 4 + r][n]      = acc0[r];
            s_S[16 + h4 * 4 + r][n] = acc1[r];
        }
        __syncthreads();   // also guarantees all waves finished reading s_x/s_h

        float hv[2];
        #pragma unroll
        for (int j = 0; j < 2; ++j) {
            int cx = ecp + j;
            float zi = s_S[eb][cx]      + s_bias[cx];
            float zf = s_S[eb][16 + cx] + s_bias[16 + cx];
            float zg = s_S[eb][32 + cx] + s_bias[32 + cx];
            float zo = s_S[eb][48 + cx] + s_bias[48 + cx];
            float ii = sigf(zi), ff = sigf(zf), gg = tanhfast(zg), oo = sigf(zo);
            float c = ff * c_reg[j] + ii * gg;
            c_reg[j] = c;
            hv[j] = oo * tanhfast(c);
        }

        if (t == T_STEPS - 1) {
            #pragma unroll
            for (int j = 0; j < 2; ++j) {
                int col = c0 + ecp + j;
                out[(size_t)eb * 1024 + d * 512 + col] = hv[j];                 // merged
                out[32768 + d * 32768 + (size_t)eb * 512 + col] = hv[j];        // h_d
                out[49152 + d * 32768 + (size_t)eb * 512 + col] = c_reg[j];     // c_d
            }
            break;
        }

        // publish h (bf16 pair) to next buffer, device-scope
        const int nb = (t + 1) & 1;
        unsigned int hp = (unsigned)f2bf(hv[0]) | ((unsigned)f2bf(hv[1]) << 16);
        unsigned int hidx = (unsigned)((d * 2 + nb) * 8192 + eb * 256 + ((c0 + ecp) >> 1));
        __hip_atomic_store(&Hbuf[hidx], hp, __ATOMIC_RELAXED, __HIP_MEMORY_SCOPE_AGENT);

        // restage next X now (no dependence on other WGs; hides under barrier)
        {
            int t_x = d ? (T_STEPS - 2 - t) : (t + 1);
            const unsigned long long* xsrc = (const unsigned long long*)(Xbf + (size_t)t_x * 32 * 256);
            #pragma unroll
            for (int i = 0; i < 8; ++i) {
                int ch = tid + i * 256;
                int b = ch >> 6;
                unsigned int addr = (unsigned)(ch * 8) ^ (unsigned)((b & 7) << 4);
                *(unsigned long long*)(s_x + addr) = xsrc[ch];
            }
        }

        __threadfence();
        __syncthreads();
        if (tid == 0) {
            __hip_atomic_fetch_add(bar, 1u, __ATOMIC_RELEASE, __HIP_MEMORY_SCOPE_AGENT);
            unsigned int target = (unsigned)NWG * (unsigned)(t + 1);
            unsigned int spin = 0;
            while (__hip_atomic_load(bar, __ATOMIC_ACQUIRE, __HIP_MEMORY_SCOPE_AGENT) < target) {
                __builtin_amdgcn_s_sleep(2);
                if (++spin > (1u << 22)) { s_abort = 1; break; }   // hang-proof: ~0.2s then bail
            }
        }
        __syncthreads();
        if (s_abort) return;   // wrong answer but guaranteed termination

        // restage H (all 512 cols) from the just-published buffer
        {
            unsigned long long* hsrc = (unsigned long long*)Hbuf + (size_t)(d * 2 + nb) * 4096;
            #pragma unroll
            for (int i = 0; i < 16; ++i) {
                int ch = tid + i * 256;
                int b = ch >> 7;
                unsigned long long v = __hip_atomic_load(&hsrc[ch], __ATOMIC_RELAXED, __HIP_MEMORY_SCOPE_AGENT);
                unsigned int addr = (unsigned)(ch * 8) ^ (unsigned)((b & 7) << 4);
                *(unsigned long long*)(s_h + addr) = v;
            }
        }
        __syncthreads();
    }
}

extern "C" void kernel_launch(void* const* d_in, const int* in_sizes, int n_in,
                              void* d_out, int out_size, void* d_ws, size_t ws_size,
                              hipStream_t stream) {
    if (ws_size < WS_NEEDED) return;   // fail loudly via unwritten output

    const float* X   = (const float*)d_in[0];
    const float* W_f = (const float*)d_in[1];
    const float* U_f = (const float*)d_in[2];
    const float* b_f = (const float*)d_in[3];
    const float* W_b = (const float*)d_in[4];
    const float* U_b = (const float*)d_in[5];
    const float* b_b = (const float*)d_in[6];

    unsigned short* Xbf = (unsigned short*)d_ws;
    unsigned int*   bar = (unsigned int*)((char*)d_ws + BAR_OFF);
    unsigned int*  Hbuf = (unsigned int*)((char*)d_ws + HBUF_OFF);

    hipMemsetAsync(bar, 0, 256, stream);
    prep_x<<<16384, 256, 0, stream>>>(X, Xbf);

    float* out = (float*)d_out;
    void* args[] = {(void*)&Xbf, (void*)&W_f, (void*)&U_f, (void*)&b_f,
                    (void*)&W_b, (void*)&U_b, (void*)&b_b,
                    (void*)&out, (void*)&bar, (void*)&Hbuf};
    hipLaunchCooperativeKernel((void*)lstm_rec, dim3(NWG), dim3(256), args, 0, stream);
}

// Round 6
// 23699.519 us; speedup vs baseline: 1.0315x; 1.0315x over previous
//
#include <hip/hip_runtime.h>

#define T_STEPS 2048
#define NWG 64

typedef __bf16 bf16x8 __attribute__((ext_vector_type(8)));
typedef float f32x4 __attribute__((ext_vector_type(4)));

// ws layout
#define XBF_OFF   0ull                       // [2048][32][256] bf16 = 33554432 B
#define FLAGS_OFF 33554432ull                // 64 flags x 128 B = 8192 B (zeroed)
#define HBUF_OFF  (FLAGS_OFF + 8192ull)      // [dir][buf][32][512] bf16 = 131072 B
#define WS_NEEDED (HBUF_OFF + 131072ull)

__device__ __forceinline__ unsigned short f2bf(float f) {
    unsigned int u = __builtin_bit_cast(unsigned int, f);
    u = u + 0x7fffu + ((u >> 16) & 1u);
    return (unsigned short)(u >> 16);
}
__device__ __forceinline__ float sigf(float x) { return 1.0f / (1.0f + __expf(-x)); }
__device__ __forceinline__ float tanhfast(float x) { return 1.0f - 2.0f / (__expf(2.0f * x) + 1.0f); }

// X: [32][2048][256] fp32 -> Xbf: [2048][32][256] bf16
__global__ void prep_x(const float* __restrict__ X, unsigned short* __restrict__ Xbf) {
    unsigned int idx = blockIdx.x * 256u + threadIdx.x;   // 4,194,304 total, 4 elems each
    unsigned int k4 = idx & 63u;
    unsigned int b  = (idx >> 6) & 31u;
    unsigned int t  = idx >> 11;
    float4 v = *(const float4*)(X + ((size_t)b * 2048u + t) * 256u + k4 * 4u);
    unsigned long long pk = (unsigned long long)f2bf(v.x)
                          | ((unsigned long long)f2bf(v.y) << 16)
                          | ((unsigned long long)f2bf(v.z) << 32)
                          | ((unsigned long long)f2bf(v.w) << 48);
    *(unsigned long long*)(Xbf + ((size_t)t * 32u + b) * 256u + k4 * 4u) = pk;
}

// Persistent recurrent kernel: 64 WGs = 2 dirs x 32 slices (16 hidden cols each).
__global__ __launch_bounds__(256, 1) void lstm_rec(
    const unsigned short* __restrict__ Xbf,
    const float* __restrict__ W_f, const float* __restrict__ U_f, const float* __restrict__ b_f,
    const float* __restrict__ W_b, const float* __restrict__ U_b, const float* __restrict__ b_b,
    float* __restrict__ out, unsigned int* flags, unsigned int* Hbuf)
{
    const int wg = blockIdx.x;
    const int d  = wg >> 5;        // 0 = forward, 1 = backward
    const int s  = wg & 31;
    const int c0 = s * 16;
    const int tid = threadIdx.x;

    const float* Wm = d ? W_b : W_f;
    const float* Um = d ? U_b : U_f;
    const float* bia = d ? b_b : b_f;

    __shared__ __align__(16) unsigned char s_u[65536];   // U slice  [64 cols][512 k] bf16, swizzled
    __shared__ __align__(16) unsigned char s_w[32768];   // W slice  [64 cols][256 k] bf16, swizzled
    __shared__ __align__(16) unsigned char s_h[32768];   // H stage  [32 b][512 k]  bf16, swizzled
    __shared__ __align__(16) unsigned char s_x[16384];   // X stage  [32 b][256 k]  bf16, swizzled
    __shared__ float s_S[32][64];                        // gate pre-activations
    __shared__ float s_bias[64];
    __shared__ int s_abort;

    // ---- prologue: stage U/W slices (fp32 global -> bf16 LDS, XOR-swizzled) ----
    {
        int cl = tid & 15, g = (tid >> 4) & 3, k0 = tid >> 6;
        int n = g * 16 + cl;
        int gcol = g * 512 + c0 + cl;
        for (int i = 0; i < 128; ++i) {
            int k = k0 + i * 4;
            unsigned short v = f2bf(Um[(size_t)k * 2048 + gcol]);
            unsigned int addr = (unsigned)(n * 1024 + k * 2) ^ (unsigned)((n & 7) << 4);
            *(unsigned short*)(s_u + addr) = v;
        }
        for (int i = 0; i < 64; ++i) {
            int k = k0 + i * 4;
            unsigned short v = f2bf(Wm[(size_t)k * 2048 + gcol]);
            unsigned int addr = (unsigned)(n * 512 + k * 2) ^ (unsigned)((n & 7) << 4);
            *(unsigned short*)(s_w + addr) = v;
        }
        if (tid < 64) s_bias[tid] = bia[(tid >> 4) * 512 + c0 + (tid & 15)];
        if (tid == 0) s_abort = 0;
        // h0 = 0
        for (int i = 0; i < 16; ++i)
            *(unsigned long long*)(s_h + (tid + i * 256) * 8) = 0ull;
        // stage x for first step
        int t_x = d ? (T_STEPS - 1) : 0;
        const unsigned long long* xsrc = (const unsigned long long*)(Xbf + (size_t)t_x * 32 * 256);
        for (int i = 0; i < 8; ++i) {
            int ch = tid + i * 256;
            int b = ch >> 6;
            unsigned int addr = (unsigned)(ch * 8) ^ (unsigned)((b & 7) << 4);
            *(unsigned long long*)(s_x + addr) = xsrc[ch];
        }
    }
    __syncthreads();

    // per-thread MFMA addressing (16x16x32 bf16: A row = l&15, k = 8*(l>>4)+j)
    const int g  = tid >> 6;          // wave == gate
    const int l  = tid & 63;
    const int cl = l & 15;
    const int h4 = l >> 4;
    const int n  = g * 16 + cl;
    // UNswizzled bases + per-lane swizzle constants (XOR applied to FULL offset)
    const unsigned int uO = (unsigned)(n * 1024 + h4 * 16);
    const unsigned int wO = (unsigned)(n * 512  + h4 * 16);
    const unsigned int nS = (unsigned)((n & 7) << 4);
    const int b0 = cl, b1 = cl + 16;
    const unsigned int hO0 = (unsigned)(b0 * 1024 + h4 * 16);
    const unsigned int hO1 = (unsigned)(b1 * 1024 + h4 * 16);
    const unsigned int xO0 = (unsigned)(b0 * 512  + h4 * 16);
    const unsigned int xO1 = (unsigned)(b1 * 512  + h4 * 16);
    const unsigned int bS0 = (unsigned)((b0 & 7) << 4);
    const unsigned int bS1 = (unsigned)((b1 & 7) << 4);

    // flag slot this WG owns (128B stride) and the slot wave-0 lanes poll
    const unsigned int myFlag   = (unsigned)(wg * 32);
    const unsigned int pollFlag = (unsigned)((d * 32 + (l & 31)) * 32);

    // elementwise mapping: thread -> (batch eb, cols ecp, ecp+1)
    const int eb  = tid >> 3;
    const int ecp = (tid & 7) * 2;
    float c_reg[2] = {0.f, 0.f};

    for (int t = 0; t < T_STEPS; ++t) {
        f32x4 acc0 = {0.f, 0.f, 0.f, 0.f};
        f32x4 acc1 = {0.f, 0.f, 0.f, 0.f};
        #pragma unroll
        for (int kc = 0; kc < 8; ++kc) {       // x @ W  (K = 256)
            bf16x8 bv = *(const bf16x8*)(s_w + ((wO + kc * 64) ^ nS));
            bf16x8 a0 = *(const bf16x8*)(s_x + ((xO0 + kc * 64) ^ bS0));
            bf16x8 a1 = *(const bf16x8*)(s_x + ((xO1 + kc * 64) ^ bS1));
            acc0 = __builtin_amdgcn_mfma_f32_16x16x32_bf16(a0, bv, acc0, 0, 0, 0);
            acc1 = __builtin_amdgcn_mfma_f32_16x16x32_bf16(a1, bv, acc1, 0, 0, 0);
        }
        #pragma unroll
        for (int kc = 0; kc < 16; ++kc) {      // h @ U  (K = 512)
            bf16x8 bv = *(const bf16x8*)(s_u + ((uO + kc * 64) ^ nS));
            bf16x8 a0 = *(const bf16x8*)(s_h + ((hO0 + kc * 64) ^ bS0));
            bf16x8 a1 = *(const bf16x8*)(s_h + ((hO1 + kc * 64) ^ bS1));
            acc0 = __builtin_amdgcn_mfma_f32_16x16x32_bf16(a0, bv, acc0, 0, 0, 0);
            acc1 = __builtin_amdgcn_mfma_f32_16x16x32_bf16(a1, bv, acc1, 0, 0, 0);
        }
        // C/D layout: row = h4*4+r, col = l&15
        #pragma unroll
        for (int r = 0; r < 4; ++r) {
            s_S[h4 * 4 + r][n]      = acc0[r];
            s_S[16 + h4 * 4 + r][n] = acc1[r];
        }
        __syncthreads();   // also guarantees all waves finished reading s_x/s_h

        float hv[2];
        #pragma unroll
        for (int j = 0; j < 2; ++j) {
            int cx = ecp + j;
            float zi = s_S[eb][cx]      + s_bias[cx];
            float zf = s_S[eb][16 + cx] + s_bias[16 + cx];
            float zg = s_S[eb][32 + cx] + s_bias[32 + cx];
            float zo = s_S[eb][48 + cx] + s_bias[48 + cx];
            float ii = sigf(zi), ff = sigf(zf), gg = tanhfast(zg), oo = sigf(zo);
            float c = ff * c_reg[j] + ii * gg;
            c_reg[j] = c;
            hv[j] = oo * tanhfast(c);
        }

        if (t == T_STEPS - 1) {
            #pragma unroll
            for (int j = 0; j < 2; ++j) {
                int col = c0 + ecp + j;
                out[(size_t)eb * 1024 + d * 512 + col] = hv[j];                 // merged
                out[32768 + d * 32768 + (size_t)eb * 512 + col] = hv[j];        // h_d
                out[49152 + d * 32768 + (size_t)eb * 512 + col] = c_reg[j];     // c_d
            }
            break;
        }

        // publish h (bf16 pair) to next buffer, device-scope
        const int nb = (t + 1) & 1;
        unsigned int hp = (unsigned)f2bf(hv[0]) | ((unsigned)f2bf(hv[1]) << 16);
        unsigned int hidx = (unsigned)((d * 2 + nb) * 8192 + eb * 256 + ((c0 + ecp) >> 1));
        __hip_atomic_store(&Hbuf[hidx], hp, __ATOMIC_RELAXED, __HIP_MEMORY_SCOPE_AGENT);

        // restage next X now (no dependence on other WGs; hides under barrier)
        {
            int t_x = d ? (T_STEPS - 2 - t) : (t + 1);
            const unsigned long long* xsrc = (const unsigned long long*)(Xbf + (size_t)t_x * 32 * 256);
            #pragma unroll
            for (int i = 0; i < 8; ++i) {
                int ch = tid + i * 256;
                int b = ch >> 6;
                unsigned int addr = (unsigned)(ch * 8) ^ (unsigned)((b & 7) << 4);
                *(unsigned long long*)(s_x + addr) = xsrc[ch];
            }
        }

        __threadfence();
        __syncthreads();
        // distributed barrier: own-slot release store, wave 0 polls own direction's 32 flags
        const unsigned int target = (unsigned)(t + 1);
        if (tid == 0)
            __hip_atomic_store(&flags[myFlag], target, __ATOMIC_RELEASE, __HIP_MEMORY_SCOPE_AGENT);
        if (tid < 64) {
            unsigned int spin = 0;
            unsigned int v = __hip_atomic_load(&flags[pollFlag], __ATOMIC_ACQUIRE, __HIP_MEMORY_SCOPE_AGENT);
            while (!__all((int)(v >= target))) {
                __builtin_amdgcn_s_sleep(1);
                v = __hip_atomic_load(&flags[pollFlag], __ATOMIC_ACQUIRE, __HIP_MEMORY_SCOPE_AGENT);
                if (++spin > (1u << 21)) { s_abort = 1; break; }   // hang-proof (~0.5s max)
            }
        }
        __syncthreads();
        if (s_abort) return;   // wrong answer but guaranteed termination

        // restage H (all 512 cols) from the just-published buffer
        {
            unsigned long long* hsrc = (unsigned long long*)Hbuf + (size_t)(d * 2 + nb) * 4096;
            #pragma unroll
            for (int i = 0; i < 16; ++i) {
                int ch = tid + i * 256;
                int b = ch >> 7;
                unsigned long long v = __hip_atomic_load(&hsrc[ch], __ATOMIC_RELAXED, __HIP_MEMORY_SCOPE_AGENT);
                unsigned int addr = (unsigned)(ch * 8) ^ (unsigned)((b & 7) << 4);
                *(unsigned long long*)(s_h + addr) = v;
            }
        }
        __syncthreads();
    }
}

extern "C" void kernel_launch(void* const* d_in, const int* in_sizes, int n_in,
                              void* d_out, int out_size, void* d_ws, size_t ws_size,
                              hipStream_t stream) {
    if (ws_size < WS_NEEDED) return;   // fail loudly via unwritten output

    const float* X   = (const float*)d_in[0];
    const float* W_f = (const float*)d_in[1];
    const float* U_f = (const float*)d_in[2];
    const float* b_f = (const float*)d_in[3];
    const float* W_b = (const float*)d_in[4];
    const float* U_b = (const float*)d_in[5];
    const float* b_b = (const float*)d_in[6];

    unsigned short* Xbf  = (unsigned short*)d_ws;
    unsigned int*  flags = (unsigned int*)((char*)d_ws + FLAGS_OFF);
    unsigned int*  Hbuf  = (unsigned int*)((char*)d_ws + HBUF_OFF);

    hipMemsetAsync(flags, 0, 8192, stream);
    prep_x<<<16384, 256, 0, stream>>>(X, Xbf);

    float* out = (float*)d_out;
    void* args[] = {(void*)&Xbf, (void*)&W_f, (void*)&U_f, (void*)&b_f,
                    (void*)&W_b, (void*)&U_b, (void*)&b_b,
                    (void*)&out, (void*)&flags, (void*)&Hbuf};
    hipLaunchCooperativeKernel((void*)lstm_rec, dim3(NWG), dim3(256), args, 0, stream);
}

// Round 7
// 13605.864 us; speedup vs baseline: 1.7967x; 1.7419x over previous
//
#include <hip/hip_runtime.h>

#define T_STEPS 2048
#define NWG 64

typedef __bf16 bf16x8 __attribute__((ext_vector_type(8)));
typedef float f32x4 __attribute__((ext_vector_type(4)));

// ws layout
#define XBF_OFF   0ull                       // [2048][32][256] bf16 = 33554432 B
#define FLAGS_OFF 33554432ull                // 64 flags x 128 B = 8192 B (zeroed)
#define HBUF_OFF  (FLAGS_OFF + 8192ull)      // [dir][buf][32][512] bf16 = 131072 B
#define WS_NEEDED (HBUF_OFF + 131072ull)

__device__ __forceinline__ unsigned short f2bf(float f) {
    unsigned int u = __builtin_bit_cast(unsigned int, f);
    u = u + 0x7fffu + ((u >> 16) & 1u);
    return (unsigned short)(u >> 16);
}
__device__ __forceinline__ float sigf(float x) { return 1.0f / (1.0f + __expf(-x)); }
__device__ __forceinline__ float tanhfast(float x) { return 1.0f - 2.0f / (__expf(2.0f * x) + 1.0f); }

// X: [32][2048][256] fp32 -> Xbf: [2048][32][256] bf16
__global__ void prep_x(const float* __restrict__ X, unsigned short* __restrict__ Xbf) {
    unsigned int idx = blockIdx.x * 256u + threadIdx.x;
    unsigned int k4 = idx & 63u;
    unsigned int b  = (idx >> 6) & 31u;
    unsigned int t  = idx >> 11;
    float4 v = *(const float4*)(X + ((size_t)b * 2048u + t) * 256u + k4 * 4u);
    unsigned long long pk = (unsigned long long)f2bf(v.x)
                          | ((unsigned long long)f2bf(v.y) << 16)
                          | ((unsigned long long)f2bf(v.z) << 32)
                          | ((unsigned long long)f2bf(v.w) << 48);
    *(unsigned long long*)(Xbf + ((size_t)t * 32u + b) * 256u + k4 * 4u) = pk;
}

// Persistent recurrent kernel: 64 WGs = 2 dirs x 32 slices (16 hidden cols each).
__global__ __launch_bounds__(256, 1) void lstm_rec(
    const unsigned short* __restrict__ Xbf,
    const float* __restrict__ W_f, const float* __restrict__ U_f, const float* __restrict__ b_f,
    const float* __restrict__ W_b, const float* __restrict__ U_b, const float* __restrict__ b_b,
    float* __restrict__ out, unsigned int* flags, unsigned int* Hbuf)
{
    const int wg = blockIdx.x;
    const int d  = wg >> 5;        // 0 = forward, 1 = backward
    const int s  = wg & 31;
    const int c0 = s * 16;
    const int tid = threadIdx.x;

    const float* Wm = d ? W_b : W_f;
    const float* Um = d ? U_b : U_f;
    const float* bia = d ? b_b : b_f;

    __shared__ __align__(16) unsigned char s_u[65536];   // U slice  [64 cols][512 k] bf16, swizzled
    __shared__ __align__(16) unsigned char s_w[32768];   // W slice  [64 cols][256 k] bf16, swizzled
    __shared__ __align__(16) unsigned char s_h[32768];   // H stage  [32 b][512 k]  bf16, swizzled
    __shared__ __align__(16) unsigned char s_x[16384];   // X stage  [32 b][256 k]  bf16, swizzled
    __shared__ float s_S[32][64];                        // gate pre-activations
    __shared__ float s_bias[64];
    __shared__ int s_abort;

    // ---- prologue: stage U/W slices (fp32 global -> bf16 LDS, XOR-swizzled) ----
    {
        int cl = tid & 15, g = (tid >> 4) & 3, k0 = tid >> 6;
        int n = g * 16 + cl;
        int gcol = g * 512 + c0 + cl;
        for (int i = 0; i < 128; ++i) {
            int k = k0 + i * 4;
            unsigned short v = f2bf(Um[(size_t)k * 2048 + gcol]);
            unsigned int addr = (unsigned)(n * 1024 + k * 2) ^ (unsigned)((n & 7) << 4);
            *(unsigned short*)(s_u + addr) = v;
        }
        for (int i = 0; i < 64; ++i) {
            int k = k0 + i * 4;
            unsigned short v = f2bf(Wm[(size_t)k * 2048 + gcol]);
            unsigned int addr = (unsigned)(n * 512 + k * 2) ^ (unsigned)((n & 7) << 4);
            *(unsigned short*)(s_w + addr) = v;
        }
        if (tid < 64) s_bias[tid] = bia[(tid >> 4) * 512 + c0 + (tid & 15)];
        if (tid == 0) s_abort = 0;
        // h0 = 0
        for (int i = 0; i < 16; ++i)
            *(unsigned long long*)(s_h + (tid + i * 256) * 8) = 0ull;
        // stage x for first step
        int t_x = d ? (T_STEPS - 1) : 0;
        const unsigned long long* xsrc = (const unsigned long long*)(Xbf + (size_t)t_x * 32 * 256);
        for (int i = 0; i < 8; ++i) {
            int ch = tid + i * 256;
            int b = ch >> 6;
            unsigned int addr = (unsigned)(ch * 8) ^ (unsigned)((b & 7) << 4);
            *(unsigned long long*)(s_x + addr) = xsrc[ch];
        }
    }
    __syncthreads();

    // per-thread MFMA addressing (16x16x32 bf16: A row = l&15, k = 8*(l>>4)+j)
    const int g  = tid >> 6;          // wave == gate
    const int l  = tid & 63;
    const int cl = l & 15;
    const int h4 = l >> 4;
    const int n  = g * 16 + cl;
    const unsigned int uO = (unsigned)(n * 1024 + h4 * 16);
    const unsigned int wO = (unsigned)(n * 512  + h4 * 16);
    const unsigned int nS = (unsigned)((n & 7) << 4);
    const int b0 = cl, b1 = cl + 16;
    const unsigned int hO0 = (unsigned)(b0 * 1024 + h4 * 16);
    const unsigned int hO1 = (unsigned)(b1 * 1024 + h4 * 16);
    const unsigned int xO0 = (unsigned)(b0 * 512  + h4 * 16);
    const unsigned int xO1 = (unsigned)(b1 * 512  + h4 * 16);
    const unsigned int bS0 = (unsigned)((b0 & 7) << 4);
    const unsigned int bS1 = (unsigned)((b1 & 7) << 4);

    // flag slot this WG owns (128B stride) and the slot wave-0 lanes poll
    const unsigned int myFlag   = (unsigned)(wg * 32);
    const unsigned int pollFlag = (unsigned)((d * 32 + (l & 31)) * 32);

    // elementwise mapping
    const int eb  = tid >> 3;
    const int ecp = (tid & 7) * 2;
    float c_reg[2] = {0.f, 0.f};

    // ---- pin loop-invariant B fragments (U/W columns) in registers ----
    bf16x8 wBr[8];
    #pragma unroll
    for (int kc = 0; kc < 8; ++kc)
        wBr[kc] = *(const bf16x8*)(s_w + ((wO + kc * 64) ^ nS));
    bf16x8 uBr[16];
    #pragma unroll
    for (int kc = 0; kc < 16; ++kc)
        uBr[kc] = *(const bf16x8*)(s_u + ((uO + kc * 64) ^ nS));

    // ---- accX(0): x(0) @ W, computed before the loop ----
    f32x4 axc0 = {0.f, 0.f, 0.f, 0.f};
    f32x4 axc1 = {0.f, 0.f, 0.f, 0.f};
    #pragma unroll
    for (int kc = 0; kc < 8; ++kc) {
        bf16x8 a0 = *(const bf16x8*)(s_x + ((xO0 + kc * 64) ^ bS0));
        bf16x8 a1 = *(const bf16x8*)(s_x + ((xO1 + kc * 64) ^ bS1));
        axc0 = __builtin_amdgcn_mfma_f32_16x16x32_bf16(a0, wBr[kc], axc0, 0, 0, 0);
        axc1 = __builtin_amdgcn_mfma_f32_16x16x32_bf16(a1, wBr[kc], axc1, 0, 0, 0);
    }

    for (int t = 0; t < T_STEPS; ++t) {
        if (t > 0) {
            // ---- wait for h(t): RELAXED poll (no per-iteration L2 invalidate) ----
            if (tid < 64) {
                unsigned int spin = 0;
                unsigned int v = __hip_atomic_load(&flags[pollFlag], __ATOMIC_RELAXED, __HIP_MEMORY_SCOPE_AGENT);
                while (!__all((int)(v >= (unsigned)t))) {
                    __builtin_amdgcn_s_sleep(1);
                    v = __hip_atomic_load(&flags[pollFlag], __ATOMIC_RELAXED, __HIP_MEMORY_SCOPE_AGENT);
                    if (++spin > (1u << 21)) { s_abort = 1; break; }   // hang-proof
                }
            }
            __syncthreads();
            if (s_abort) return;
            // ---- restage h(t) from Hbuf[buf = t&1] (sc1 loads hit coherence point) ----
            unsigned long long* hsrc = (unsigned long long*)Hbuf + (size_t)(d * 2 + (t & 1)) * 4096;
            #pragma unroll
            for (int i = 0; i < 16; ++i) {
                int ch = tid + i * 256;
                int b = ch >> 7;
                unsigned long long v = __hip_atomic_load(&hsrc[ch], __ATOMIC_RELAXED, __HIP_MEMORY_SCOPE_AGENT);
                unsigned int addr = (unsigned)(ch * 8) ^ (unsigned)((b & 7) << 4);
                *(unsigned long long*)(s_h + addr) = v;
            }
            __syncthreads();
        }

        // ---- post-barrier critical path: only the U MFMAs ----
        f32x4 acc0 = axc0;
        f32x4 acc1 = axc1;
        #pragma unroll
        for (int kc = 0; kc < 16; ++kc) {      // h @ U  (K = 512)
            bf16x8 a0 = *(const bf16x8*)(s_h + ((hO0 + kc * 64) ^ bS0));
            bf16x8 a1 = *(const bf16x8*)(s_h + ((hO1 + kc * 64) ^ bS1));
            acc0 = __builtin_amdgcn_mfma_f32_16x16x32_bf16(a0, uBr[kc], acc0, 0, 0, 0);
            acc1 = __builtin_amdgcn_mfma_f32_16x16x32_bf16(a1, uBr[kc], acc1, 0, 0, 0);
        }
        // C/D layout: row = h4*4+r, col = l&15
        #pragma unroll
        for (int r = 0; r < 4; ++r) {
            s_S[h4 * 4 + r][n]      = acc0[r];
            s_S[16 + h4 * 4 + r][n] = acc1[r];
        }
        __syncthreads();

        float hv[2];
        #pragma unroll
        for (int j = 0; j < 2; ++j) {
            int cx = ecp + j;
            float zi = s_S[eb][cx]      + s_bias[cx];
            float zf = s_S[eb][16 + cx] + s_bias[16 + cx];
            float zg = s_S[eb][32 + cx] + s_bias[32 + cx];
            float zo = s_S[eb][48 + cx] + s_bias[48 + cx];
            float ii = sigf(zi), ff = sigf(zf), gg = tanhfast(zg), oo = sigf(zo);
            float c = ff * c_reg[j] + ii * gg;
            c_reg[j] = c;
            hv[j] = oo * tanhfast(c);
        }

        if (t == T_STEPS - 1) {
            #pragma unroll
            for (int j = 0; j < 2; ++j) {
                int col = c0 + ecp + j;
                out[(size_t)eb * 1024 + d * 512 + col] = hv[j];                 // merged
                out[32768 + d * 32768 + (size_t)eb * 512 + col] = hv[j];        // h_d
                out[49152 + d * 32768 + (size_t)eb * 512 + col] = c_reg[j];     // c_d
            }
            break;
        }

        // ---- publish h(t+1) (sc1 stores go to coherence point) ----
        const int nb = (t + 1) & 1;
        unsigned int hp = (unsigned)f2bf(hv[0]) | ((unsigned)f2bf(hv[1]) << 16);
        unsigned int hidx = (unsigned)((d * 2 + nb) * 8192 + eb * 256 + ((c0 + ecp) >> 1));
        __hip_atomic_store(&Hbuf[hidx], hp, __ATOMIC_RELAXED, __HIP_MEMORY_SCOPE_AGENT);

        // barrier drains each wave's vmcnt -> all publishes complete, then one
        // RELEASE flag store (single wbl2/step, no threadfence)
        __syncthreads();
        if (tid == 0)
            __hip_atomic_store(&flags[myFlag], (unsigned)(t + 1), __ATOMIC_RELEASE, __HIP_MEMORY_SCOPE_AGENT);

        // ---- wait-shadow work: restage x(t+1), compute x@W for step t+1 ----
        {
            int t_x = d ? (T_STEPS - 2 - t) : (t + 1);
            const unsigned long long* xsrc = (const unsigned long long*)(Xbf + (size_t)t_x * 32 * 256);
            #pragma unroll
            for (int i = 0; i < 8; ++i) {
                int ch = tid + i * 256;
                int b = ch >> 6;
                unsigned int addr = (unsigned)(ch * 8) ^ (unsigned)((b & 7) << 4);
                *(unsigned long long*)(s_x + addr) = xsrc[ch];
            }
        }
        __syncthreads();
        axc0 = f32x4{0.f, 0.f, 0.f, 0.f};
        axc1 = f32x4{0.f, 0.f, 0.f, 0.f};
        #pragma unroll
        for (int kc = 0; kc < 8; ++kc) {       // x(t+1) @ W in the wait shadow
            bf16x8 a0 = *(const bf16x8*)(s_x + ((xO0 + kc * 64) ^ bS0));
            bf16x8 a1 = *(const bf16x8*)(s_x + ((xO1 + kc * 64) ^ bS1));
            axc0 = __builtin_amdgcn_mfma_f32_16x16x32_bf16(a0, wBr[kc], axc0, 0, 0, 0);
            axc1 = __builtin_amdgcn_mfma_f32_16x16x32_bf16(a1, wBr[kc], axc1, 0, 0, 0);
        }
    }
}

extern "C" void kernel_launch(void* const* d_in, const int* in_sizes, int n_in,
                              void* d_out, int out_size, void* d_ws, size_t ws_size,
                              hipStream_t stream) {
    if (ws_size < WS_NEEDED) return;   // fail loudly via unwritten output

    const float* X   = (const float*)d_in[0];
    const float* W_f = (const float*)d_in[1];
    const float* U_f = (const float*)d_in[2];
    const float* b_f = (const float*)d_in[3];
    const float* W_b = (const float*)d_in[4];
    const float* U_b = (const float*)d_in[5];
    const float* b_b = (const float*)d_in[6];

    unsigned short* Xbf  = (unsigned short*)d_ws;
    unsigned int*  flags = (unsigned int*)((char*)d_ws + FLAGS_OFF);
    unsigned int*  Hbuf  = (unsigned int*)((char*)d_ws + HBUF_OFF);

    hipMemsetAsync(flags, 0, 8192, stream);
    prep_x<<<16384, 256, 0, stream>>>(X, Xbf);

    float* out = (float*)d_out;
    void* args[] = {(void*)&Xbf, (void*)&W_f, (void*)&U_f, (void*)&b_f,
                    (void*)&W_b, (void*)&U_b, (void*)&b_b,
                    (void*)&out, (void*)&flags, (void*)&Hbuf};
    hipLaunchCooperativeKernel((void*)lstm_rec, dim3(NWG), dim3(256), args, 0, stream);
}

// Round 9
// 12649.337 us; speedup vs baseline: 1.9326x; 1.0756x over previous
//
#include <hip/hip_runtime.h>

#define T_STEPS 2048
#define NWG 64

typedef __bf16 bf16x8 __attribute__((ext_vector_type(8)));
typedef float f32x4 __attribute__((ext_vector_type(4)));

// ws layout
#define XBF_OFF   0ull                       // [2048][32][256] bf16 = 33554432 B
#define FLAGS_OFF 33554432ull                // 64 flags x 128 B = 8192 B (zeroed)
#define HBUF_OFF  (FLAGS_OFF + 8192ull)      // [dir][buf][32][512] bf16 = 131072 B
#define WS_NEEDED (HBUF_OFF + 131072ull)

__device__ __forceinline__ unsigned short f2bf(float f) {
    unsigned int u = __builtin_bit_cast(unsigned int, f);
    u = u + 0x7fffu + ((u >> 16) & 1u);
    return (unsigned short)(u >> 16);
}
__device__ __forceinline__ float sigf(float x) { return 1.0f / (1.0f + __expf(-x)); }
__device__ __forceinline__ float tanhfast(float x) { return 1.0f - 2.0f / (__expf(2.0f * x) + 1.0f); }

// X: [32][2048][256] fp32 -> Xbf: [2048][32][256] bf16
__global__ void prep_x(const float* __restrict__ X, unsigned short* __restrict__ Xbf) {
    unsigned int idx = blockIdx.x * 256u + threadIdx.x;
    unsigned int k4 = idx & 63u;
    unsigned int b  = (idx >> 6) & 31u;
    unsigned int t  = idx >> 11;
    float4 v = *(const float4*)(X + ((size_t)b * 2048u + t) * 256u + k4 * 4u);
    unsigned long long pk = (unsigned long long)f2bf(v.x)
                          | ((unsigned long long)f2bf(v.y) << 16)
                          | ((unsigned long long)f2bf(v.z) << 32)
                          | ((unsigned long long)f2bf(v.w) << 48);
    *(unsigned long long*)(Xbf + ((size_t)t * 32u + b) * 256u + k4 * 4u) = pk;
}

// Persistent recurrent kernel: 64 WGs = 2 dirs x 32 slices (16 hidden cols each).
__global__ __launch_bounds__(256, 1) void lstm_rec(
    const unsigned short* __restrict__ Xbf,
    const float* __restrict__ W_f, const float* __restrict__ U_f, const float* __restrict__ b_f,
    const float* __restrict__ W_b, const float* __restrict__ U_b, const float* __restrict__ b_b,
    float* __restrict__ out, unsigned int* flags, unsigned int* Hbuf)
{
    const int wg = blockIdx.x;
    const int d  = wg >> 5;        // 0 = forward, 1 = backward
    const int s  = wg & 31;
    const int c0 = s * 16;
    const int tid = threadIdx.x;

    const float* Wm = d ? W_b : W_f;
    const float* Um = d ? U_b : U_f;
    const float* bia = d ? b_b : b_f;

    __shared__ __align__(16) unsigned char s_u[65536];   // U slice  [64 cols][512 k] bf16, swizzled
    __shared__ __align__(16) unsigned char s_w[32768];   // W slice  [64 cols][256 k] bf16, swizzled
    __shared__ __align__(16) unsigned char s_h[32768];   // H stage  [32 b][512 k]  bf16, swizzled
    __shared__ __align__(16) unsigned char s_x[16384];   // X stage  [32 b][256 k]  bf16, swizzled
    __shared__ float s_S[32][64];                        // gate pre-activations
    __shared__ float s_bias[64];
    __shared__ int s_abort;

    // ---- prologue: stage U/W slices (fp32 global -> bf16 LDS, XOR-swizzled) ----
    {
        int cl = tid & 15, g = (tid >> 4) & 3, k0 = tid >> 6;
        int n = g * 16 + cl;
        int gcol = g * 512 + c0 + cl;
        for (int i = 0; i < 128; ++i) {
            int k = k0 + i * 4;
            unsigned short v = f2bf(Um[(size_t)k * 2048 + gcol]);
            unsigned int addr = (unsigned)(n * 1024 + k * 2) ^ (unsigned)((n & 7) << 4);
            *(unsigned short*)(s_u + addr) = v;
        }
        for (int i = 0; i < 64; ++i) {
            int k = k0 + i * 4;
            unsigned short v = f2bf(Wm[(size_t)k * 2048 + gcol]);
            unsigned int addr = (unsigned)(n * 512 + k * 2) ^ (unsigned)((n & 7) << 4);
            *(unsigned short*)(s_w + addr) = v;
        }
        if (tid < 64) s_bias[tid] = bia[(tid >> 4) * 512 + c0 + (tid & 15)];
        if (tid == 0) s_abort = 0;
        // h0 = 0
        for (int i = 0; i < 16; ++i)
            *(unsigned long long*)(s_h + (tid + i * 256) * 8) = 0ull;
        // stage x for first step
        int t_x = d ? (T_STEPS - 1) : 0;
        const unsigned long long* xsrc = (const unsigned long long*)(Xbf + (size_t)t_x * 32 * 256);
        for (int i = 0; i < 8; ++i) {
            int ch = tid + i * 256;
            int b = ch >> 6;
            unsigned int addr = (unsigned)(ch * 8) ^ (unsigned)((b & 7) << 4);
            *(unsigned long long*)(s_x + addr) = xsrc[ch];
        }
    }
    __syncthreads();

    // per-thread MFMA addressing (16x16x32 bf16: A row = l&15, k = 8*(l>>4)+j)
    const int g  = tid >> 6;          // wave == gate
    const int l  = tid & 63;
    const int cl = l & 15;
    const int h4 = l >> 4;
    const int n  = g * 16 + cl;
    const unsigned int uO = (unsigned)(n * 1024 + h4 * 16);
    const unsigned int wO = (unsigned)(n * 512  + h4 * 16);
    const unsigned int nS = (unsigned)((n & 7) << 4);
    const int b0 = cl, b1 = cl + 16;
    const unsigned int hO0 = (unsigned)(b0 * 1024 + h4 * 16);
    const unsigned int hO1 = (unsigned)(b1 * 1024 + h4 * 16);
    const unsigned int xO0 = (unsigned)(b0 * 512  + h4 * 16);
    const unsigned int xO1 = (unsigned)(b1 * 512  + h4 * 16);
    const unsigned int bS0 = (unsigned)((b0 & 7) << 4);
    const unsigned int bS1 = (unsigned)((b1 & 7) << 4);

    // flag slot this WG owns (128B stride); every wave polls all 32 of its dir
    const unsigned int myFlag   = (unsigned)(wg * 32);
    const unsigned int pollFlag = (unsigned)((d * 32 + (l & 31)) * 32);

    // elementwise mapping
    const int eb  = tid >> 3;
    const int ecp = (tid & 7) * 2;
    float c_reg[2] = {0.f, 0.f};

    // ---- pin loop-invariant B fragments (U/W columns) in registers ----
    bf16x8 wBr[8];
    #pragma unroll
    for (int kc = 0; kc < 8; ++kc)
        wBr[kc] = *(const bf16x8*)(s_w + ((wO + kc * 64) ^ nS));
    bf16x8 uBr[16];
    #pragma unroll
    for (int kc = 0; kc < 16; ++kc)
        uBr[kc] = *(const bf16x8*)(s_u + ((uO + kc * 64) ^ nS));

    // ---- accX(0): x(0) @ W, computed before the loop ----
    f32x4 axc0 = {0.f, 0.f, 0.f, 0.f};
    f32x4 axc1 = {0.f, 0.f, 0.f, 0.f};
    #pragma unroll
    for (int kc = 0; kc < 8; ++kc) {
        bf16x8 a0 = *(const bf16x8*)(s_x + ((xO0 + kc * 64) ^ bS0));
        bf16x8 a1 = *(const bf16x8*)(s_x + ((xO1 + kc * 64) ^ bS1));
        axc0 = __builtin_amdgcn_mfma_f32_16x16x32_bf16(a0, wBr[kc], axc0, 0, 0, 0);
        axc1 = __builtin_amdgcn_mfma_f32_16x16x32_bf16(a1, wBr[kc], axc1, 0, 0, 0);
    }

    for (int t = 0; t < T_STEPS; ++t) {
        if (t > 0) {
            // ---- all waves poll (RELAXED, no cache maintenance) ----
            {
                unsigned int spin = 0;
                unsigned int v = __hip_atomic_load(&flags[pollFlag], __ATOMIC_RELAXED, __HIP_MEMORY_SCOPE_AGENT);
                while (!__all((int)(v >= (unsigned)t))) {
                    __builtin_amdgcn_s_sleep(1);
                    v = __hip_atomic_load(&flags[pollFlag], __ATOMIC_RELAXED, __HIP_MEMORY_SCOPE_AGENT);
                    if (++spin > (1u << 21)) { s_abort = 1; break; }   // hang-proof
                }
            }
            // ---- restage h(t) immediately (per-wave, no barrier first) ----
            unsigned long long* hsrc = (unsigned long long*)Hbuf + (size_t)(d * 2 + (t & 1)) * 4096;
            #pragma unroll
            for (int i = 0; i < 16; ++i) {
                int ch = tid + i * 256;
                int b = ch >> 7;
                unsigned long long v = __hip_atomic_load(&hsrc[ch], __ATOMIC_RELAXED, __HIP_MEMORY_SCOPE_AGENT);
                unsigned int addr = (unsigned)(ch * 8) ^ (unsigned)((b & 7) << 4);
                *(unsigned long long*)(s_h + addr) = v;
            }
            __syncthreads();
            if (s_abort) return;
        }

        // ---- post-barrier critical path: only the U MFMAs ----
        f32x4 acc0 = axc0;
        f32x4 acc1 = axc1;
        #pragma unroll
        for (int kc = 0; kc < 16; ++kc) {      // h @ U  (K = 512)
            bf16x8 a0 = *(const bf16x8*)(s_h + ((hO0 + kc * 64) ^ bS0));
            bf16x8 a1 = *(const bf16x8*)(s_h + ((hO1 + kc * 64) ^ bS1));
            acc0 = __builtin_amdgcn_mfma_f32_16x16x32_bf16(a0, uBr[kc], acc0, 0, 0, 0);
            acc1 = __builtin_amdgcn_mfma_f32_16x16x32_bf16(a1, uBr[kc], acc1, 0, 0, 0);
        }
        // C/D layout: row = h4*4+r, col = l&15
        #pragma unroll
        for (int r = 0; r < 4; ++r) {
            s_S[h4 * 4 + r][n]      = acc0[r];
            s_S[16 + h4 * 4 + r][n] = acc1[r];
        }
        __syncthreads();

        float hv[2];
        #pragma unroll
        for (int j = 0; j < 2; ++j) {
            int cx = ecp + j;
            float zi = s_S[eb][cx]      + s_bias[cx];
            float zf = s_S[eb][16 + cx] + s_bias[16 + cx];
            float zg = s_S[eb][32 + cx] + s_bias[32 + cx];
            float zo = s_S[eb][48 + cx] + s_bias[48 + cx];
            float ii = sigf(zi), ff = sigf(zf), gg = tanhfast(zg), oo = sigf(zo);
            float c = ff * c_reg[j] + ii * gg;
            c_reg[j] = c;
            hv[j] = oo * tanhfast(c);
        }

        if (t == T_STEPS - 1) {
            #pragma unroll
            for (int j = 0; j < 2; ++j) {
                int col = c0 + ecp + j;
                out[(size_t)eb * 1024 + d * 512 + col] = hv[j];                 // merged
                out[32768 + d * 32768 + (size_t)eb * 512 + col] = hv[j];        // h_d
                out[49152 + d * 32768 + (size_t)eb * 512 + col] = c_reg[j];     // c_d
            }
            break;
        }

        // ---- publish h(t+1) (sc1 stores go to coherence point) ----
        const int nb = (t + 1) & 1;
        unsigned int hp = (unsigned)f2bf(hv[0]) | ((unsigned)f2bf(hv[1]) << 16);
        unsigned int hidx = (unsigned)((d * 2 + nb) * 8192 + eb * 256 + ((c0 + ecp) >> 1));
        __hip_atomic_store(&Hbuf[hidx], hp, __ATOMIC_RELAXED, __HIP_MEMORY_SCOPE_AGENT);

        // barrier drains each wave's vmcnt -> all publishes acked at coherence
        // point before the flag store issues; RELAXED flag avoids buffer_wbl2.
        __syncthreads();
        if (tid == 0)
            __hip_atomic_store(&flags[myFlag], (unsigned)(t + 1), __ATOMIC_RELAXED, __HIP_MEMORY_SCOPE_AGENT);

        // ---- wait-shadow work: restage x(t+1), compute x@W for step t+1 ----
        {
            int t_x = d ? (T_STEPS - 2 - t) : (t + 1);
            const unsigned long long* xsrc = (const unsigned long long*)(Xbf + (size_t)t_x * 32 * 256);
            #pragma unroll
            for (int i = 0; i < 8; ++i) {
                int ch = tid + i * 256;
                int b = ch >> 6;
                unsigned int addr = (unsigned)(ch * 8) ^ (unsigned)((b & 7) << 4);
                *(unsigned long long*)(s_x + addr) = xsrc[ch];
            }
        }
        __syncthreads();
        axc0 = f32x4{0.f, 0.f, 0.f, 0.f};
        axc1 = f32x4{0.f, 0.f, 0.f, 0.f};
        #pragma unroll
        for (int kc = 0; kc < 8; ++kc) {       // x(t+1) @ W in the wait shadow
            bf16x8 a0 = *(const bf16x8*)(s_x + ((xO0 + kc * 64) ^ bS0));
            bf16x8 a1 = *(const bf16x8*)(s_x + ((xO1 + kc * 64) ^ bS1));
            axc0 = __builtin_amdgcn_mfma_f32_16x16x32_bf16(a0, wBr[kc], axc0, 0, 0, 0);
            axc1 = __builtin_amdgcn_mfma_f32_16x16x32_bf16(a1, wBr[kc], axc1, 0, 0, 0);
        }
    }
}

extern "C" void kernel_launch(void* const* d_in, const int* in_sizes, int n_in,
                              void* d_out, int out_size, void* d_ws, size_t ws_size,
                              hipStream_t stream) {
    if (ws_size < WS_NEEDED) return;   // fail loudly via unwritten output

    const float* X   = (const float*)d_in[0];
    const float* W_f = (const float*)d_in[1];
    const float* U_f = (const float*)d_in[2];
    const float* b_f = (const float*)d_in[3];
    const float* W_b = (const float*)d_in[4];
    const float* U_b = (const float*)d_in[5];
    const float* b_b = (const float*)d_in[6];

    unsigned short* Xbf  = (unsigned short*)d_ws;
    unsigned int*  flags = (unsigned int*)((char*)d_ws + FLAGS_OFF);
    unsigned int*  Hbuf  = (unsigned int*)((char*)d_ws + HBUF_OFF);

    hipMemsetAsync(flags, 0, 8192, stream);
    prep_x<<<16384, 256, 0, stream>>>(X, Xbf);

    float* out = (float*)d_out;
    void* args[] = {(void*)&Xbf, (void*)&W_f, (void*)&U_f, (void*)&b_f,
                    (void*)&W_b, (void*)&U_b, (void*)&b_b,
                    (void*)&out, (void*)&flags, (void*)&Hbuf};
    hipLaunchCooperativeKernel((void*)lstm_rec, dim3(NWG), dim3(256), args, 0, stream);
}